// Round 7
// baseline (84.182 us; speedup 1.0000x reference)
//
#include <hip/hip_runtime.h>

// Discrete color pick via fp32 sign tests: predicates must match numpy fp32
// rounding bit-exactly. contract(off) keeps the exact fallback exact; screens
// use explicit __builtin_fmaf with 2-sided bands + bit-exact 4-cell fallback.
//
// r7: branchless visit structure. Per point, ALL 4 candidate cell payloads are
// loaded unconditionally (clamped addresses), giving 16 independent
// ds_read_b128 per point-group with no exec branches -> full DS MLP. The
// candidate mask `act` only gates the idx/unc selects. r6's `if(act)` variant
// measured ~21 us vs a 10.4 us DS floor: latency-bound from broken MLP.
#pragma clang fp contract(off)

#define NPTS 2097152
#define PPT  4
#define NTHREADS (NPTS / PPT)   // 524288

// LDS float layout:
//   CELLS [25][20]: 16 payload floats + 4 pad (80 B stride)
//     [0..8]  tri affine: d0y,-d0x,k0, d1y,-d1x,k1, d2y,-d2x,k2  (k fp64->fp32)
//     [9..11] circle: ocx,ocy,r2(=fl(orr*orr))
//     [12..15] ellipse: ecx,ecy,1/erx,1/ery
//   COLS [76][4]: shape colors, entry 75 = black (no-hit)
#define L_COL  500
#define LDS_FLOATS (500 + 304)   // 3216 B

// Screen bands (2-sided; band hit => bit-exact fallback):
//   tri affine vs numpy |delta| <= ~1.1e-7  -> 1e-6 (9x margin)
//   circ fma   vs numpy |delta| <= ~7e-9    -> 1e-7 (14x margin)
//   ell recip  vs numpy |delta| <= ~6e-7    -> 1e-5 (validated r1-r6, absmax 0)
#define EPS_T 1e-6f
#define EPS_C 1e-7f
#define EPS_E 1e-5f

// Bit-exact numpy-order evaluation over the 4 candidate cells, reading raw
// params (fl(by-ay) etc. reproduce numpy's fp32 ops exactly). Non-candidate
// shapes are >= 5e-4 away geometrically vs fp sign-test reach ~3e-7, so the
// 4-cell restriction is exact for numpy arithmetic too. Rare (~1e-3 of pts).
__device__ __noinline__ int exact_point(float px, float py, int ih, int jh,
                                        const float* __restrict__ p) {
    int idx = -1;
#pragma clang loop unroll(disable)
    for (int s = 0; s < 4; ++s) {
        int ii = ih - 1 + (s >> 1), jj = jh - 1 + (s & 1);   // ascending cell
        if ((unsigned)ii > 4u || (unsigned)jj > 4u) continue;
        int c = 5 * ii + jj;
        const float* cell = p + 28 * c;
        float ax = cell[1], ay = cell[2], bx = cell[3], by = cell[4], cx = cell[5], cy = cell[6];
        float e0 = (px - ax) * (by - ay) - (py - ay) * (bx - ax);
        float e1 = (px - bx) * (cy - by) - (py - by) * (cx - bx);
        float e2 = (px - cx) * (ay - cy) - (py - cy) * (ax - cx);
        bool tin = (e0 >= 0.f && e1 >= 0.f && e2 >= 0.f) ||
                   (e0 <= 0.f && e1 <= 0.f && e2 <= 0.f);
        if (tin) idx = 3 * c;
        float dx = px - cell[12], dy = py - cell[13];
        if (dx * dx + dy * dy <= cell[14] * cell[14]) idx = 3 * c + 1;
        float u = (px - cell[20]) / cell[22];   // IEEE division, numpy order
        float v = (py - cell[21]) / cell[23];
        if (u * u + v * v <= 1.0f) idx = 3 * c + 2;
    }
    return idx;
}

__global__ __launch_bounds__(256) void vg_fused(const float* __restrict__ x,
                                                const float* __restrict__ p,
                                                float* __restrict__ out) {
    __shared__ float lds[LDS_FLOATS];
    int tl = threadIdx.x;
    int t  = blockIdx.x * 256 + tl;

    // ---- build packed cell table (threads 0..24) ----
    if (tl < 25) {
        const float* cell = p + tl * 28;
        float* o = lds + tl * 20;
        float ax = cell[1], ay = cell[2], bx = cell[3], by = cell[4], cx = cell[5], cy = cell[6];
        float d0y = by - ay, d0x = bx - ax;   // numpy-rounded diffs
        float d1y = cy - by, d1x = cx - bx;
        float d2y = ay - cy, d2x = ax - cx;
        o[0] = d0y; o[1] = -d0x; o[2] = (float)((double)ay * (double)d0x - (double)ax * (double)d0y);
        o[3] = d1y; o[4] = -d1x; o[5] = (float)((double)by * (double)d1x - (double)bx * (double)d1y);
        o[6] = d2y; o[7] = -d2x; o[8] = (float)((double)cy * (double)d2x - (double)cx * (double)d2y);
        o[9]  = cell[12]; o[10] = cell[13]; o[11] = cell[14] * cell[14];
        o[12] = cell[20]; o[13] = cell[21]; o[14] = 1.0f / cell[22]; o[15] = 1.0f / cell[23];
        o[16] = 0.f; o[17] = 0.f; o[18] = 0.f; o[19] = 0.f;
    }
    // ---- build color table (threads 128..203 -> entries 0..75) ----
    if (tl >= 128 && tl < 204) {
        int e = tl - 128;
        float* col = lds + L_COL + e * 4;
        if (e < 75) {
            int c = e / 3, kind = e - 3 * c;
            const float* cell = p + c * 28;
            int base = (kind == 0) ? 8 : (kind == 1) ? 16 : 25;
            col[0] = cell[base]; col[1] = cell[base + 1]; col[2] = cell[base + 2];
        } else {
            col[0] = 0.f; col[1] = 0.f; col[2] = 0.f;   // no-hit -> black
        }
        col[3] = 0.f;
    }
    __syncthreads();

    // ---- load 4 points (2 contiguous float4 per lane, coalesced) ----
    const float4* x4 = (const float4*)x;
    float4 xa = x4[2 * t], xb = x4[2 * t + 1];
    float PX[PPT] = {xa.x, xa.z, xb.x, xb.z};
    float PY[PPT] = {xa.y, xa.w, xb.y, xb.w};
    int idx[PPT], ih[PPT], jh[PPT];
    bool nxL[PPT], nyL[PPT], unc[PPT];

#pragma unroll
    for (int k = 0; k < PPT; ++k) {
        idx[k] = -1; unc[k] = false;
        // candidate real columns {ih-1, ih}; ih = floor(5X+0.4025) in [0,5].
        // left col needed iff frac <= 0.8055 (reach 0.0805 >= 0.08 + slack).
        float vx = __builtin_fmaf(PX[k], 5.0f, 0.4025f);
        float vy = __builtin_fmaf(PY[k], 5.0f, 0.4025f);
        float fx = floorf(vx), fy = floorf(vy);
        ih[k] = (int)fx; jh[k] = (int)fy;
        nxL[k] = (vx - fx) <= 0.8055f;
        nyL[k] = (vy - fy) <= 0.8055f;
    }

#pragma unroll
    for (int k = 0; k < PPT; ++k) {
        float X = PX[k], Y = PY[k];

        // Phase 1: unconditional clamped loads of all 4 candidate payloads.
        // 16 independent ds_read_b128, no branches -> full MLP.
        float4 Q[4][4];
        int  cid[4];
        bool act[4];
#pragma unroll
        for (int s = 0; s < 4; ++s) {
            int a = s >> 1, b = s & 1;
            int ii = ih[k] + a - 1, jj = jh[k] + b - 1;       // in [-1,5]
            act[s] = ((a == 1) | nxL[k]) & ((b == 1) | nyL[k]) &
                     ((unsigned)ii <= 4u) & ((unsigned)jj <= 4u);
            int iic = min(max(ii, 0), 4), jjc = min(max(jj, 0), 4);
            cid[s] = 5 * iic + jjc;                           // clamped: valid addr
            const float4* c4 = (const float4*)(lds + cid[s] * 20);
            Q[s][0] = c4[0]; Q[s][1] = c4[1]; Q[s][2] = c4[2]; Q[s][3] = c4[3];
        }

        // Phase 2: select-gated evaluation (no exec branches).
#pragma unroll
        for (int s = 0; s < 4; ++s) {
            float4 q0 = Q[s][0], q1 = Q[s][1], q2 = Q[s][2], q3 = Q[s][3];
            bool A = act[s];
            int sid = 3 * cid[s];   // == 3*(5*ii+jj) whenever A

            // triangle: affine screen, 2-sided band
            float e0 = __builtin_fmaf(X, q0.x, __builtin_fmaf(Y, q0.y, q0.z));
            float e1 = __builtin_fmaf(X, q0.w, __builtin_fmaf(Y, q1.x, q1.y));
            float e2 = __builtin_fmaf(X, q1.z, __builtin_fmaf(Y, q1.w, q2.x));
            float lo = __builtin_fminf(__builtin_fminf(e0, e1), e2);
            float hi = __builtin_fmaxf(__builtin_fmaxf(e0, e1), e2);
            bool ts = (lo >= EPS_T) || (hi <= -EPS_T);
            bool tr = (lo >= -EPS_T) || (hi <= EPS_T);
            unc[k] = unc[k] | (A & (ts != tr));
            idx[k] = (A & ts) ? sid : idx[k];

            // circle: centered fma screen
            float dx = X - q2.y, dy = Y - q2.z;
            float tc = __builtin_fmaf(dx, dx, dy * dy);
            unc[k] = unc[k] | (A & (__builtin_fabsf(tc - q2.w) < EPS_C));
            idx[k] = (A & (tc <= q2.w)) ? sid + 1 : idx[k];

            // ellipse: reciprocal screen
            float ex = X - q3.x, ey = Y - q3.y;
            float u = ex * q3.z, v = ey * q3.w;
            float te = __builtin_fmaf(u, u, v * v);
            unc[k] = unc[k] | (A & (__builtin_fabsf(te - 1.0f) < EPS_E));
            idx[k] = (A & (te <= 1.0f)) ? sid + 2 : idx[k];
        }
    }

    // rare bit-exact fallback for band-flagged points
#pragma unroll
    for (int k = 0; k < PPT; ++k)
        if (__builtin_expect(unc[k], 0))
            idx[k] = exact_point(PX[k], PY[k], ih[k], jh[k], p);

    // color gather from LDS (entry 75 = black) + packed coalesced stores
    const float4* col4 = (const float4*)(lds + L_COL);
    float4 c0 = col4[idx[0] < 0 ? 75 : idx[0]];
    float4 c1 = col4[idx[1] < 0 ? 75 : idx[1]];
    float4 c2 = col4[idx[2] < 0 ? 75 : idx[2]];
    float4 c3 = col4[idx[3] < 0 ? 75 : idx[3]];

    float4* out4 = (float4*)out;
    out4[3 * t + 0] = make_float4(c0.x, c0.y, c0.z, c1.x);
    out4[3 * t + 1] = make_float4(c1.y, c1.z, c2.x, c2.y);
    out4[3 * t + 2] = make_float4(c2.z, c3.x, c3.y, c3.z);
}

extern "C" void kernel_launch(void* const* d_in, const int* in_sizes, int n_in,
                              void* d_out, int out_size, void* d_ws, size_t ws_size,
                              hipStream_t stream) {
    const float* x = (const float*)d_in[0];   // (NPTS, 2) fp32
    const float* p = (const float*)d_in[1];   // (700,)   fp32
    float* out = (float*)d_out;               // (NPTS, 3) fp32
    (void)d_ws; (void)ws_size;

    vg_fused<<<NTHREADS / 256, 256, 0, stream>>>(x, p, out);
}

// Round 8
// 80.395 us; speedup vs baseline: 1.0471x; 1.0471x over previous
//
#include <hip/hip_runtime.h>

// Discrete color pick via fp32 sign tests: predicates must match numpy fp32
// rounding bit-exactly. contract(off) keeps the exact fallback exact; screens
// use explicit __builtin_fmaf with 2-sided bands + bit-exact 4-cell fallback.
//
// r8: fully branchless DS-gather. Padded 7x7 cell grid (dummy borders are
// geometrically inert: no hit, no band) makes all 4 candidate indices valid
// -> no clamps, no act masks (r7's regression). Spurious visits of real cells
// are safe too: hit => inside shape => within window. All 16 ds_read_b128 of
// a point share ONE address register (imm offsets 0..640+48) -> MLP=16,
// vs r6's branch-body MLP~4. PPT=2 caps VGPR (r7's other regression).
#pragma clang fp contract(off)

#define NPTS 2097152
#define PPT  2
#define NTHREADS (NPTS / PPT)   // 1048576

// LDS float layout:
//   CELLS [49][20]: padded 7x7 grid, 16 payload floats + 4 pad (80 B stride:
//     start banks cycle 0,20,8,28,16,4,24,12 -> all 8 window positions)
//     [0..8]  tri affine: d0y,-d0x,k0, d1y,-d1x,k1, d2y,-d2x,k2  (k fp64->fp32)
//     [9..11] circle: ocx,ocy,r2(=fl(orr*orr))
//     [12..15] ellipse: ecx,ecy,1/erx,1/ery
//   COLS [76][4]: shape colors, entry 75 = black (no-hit)
#define L_COL  980
#define LDS_FLOATS (980 + 304)   // 5136 B

// Screen bands (2-sided; band hit => bit-exact fallback):
//   tri affine vs numpy |delta| <= ~1.1e-7  -> 1e-6 (9x margin)
//   circ fma   vs numpy |delta| <= ~7e-9    -> 1e-7 (14x margin)
//   ell recip  vs numpy |delta| <= ~6e-7    -> 1e-5 (validated r1-r7, absmax 0)
#define EPS_T 1e-6f
#define EPS_C 1e-7f
#define EPS_E 1e-5f

// Bit-exact numpy-order evaluation over the 4 candidate cells, reading raw
// params (fl(by-ay) etc. reproduce numpy's fp32 ops exactly). Non-candidate
// shapes are >= 5e-4 away geometrically vs fp sign-test reach ~3e-7, so the
// 4-cell restriction is exact for numpy arithmetic too. Rare (~1e-3 of pts).
__device__ __noinline__ int exact_point(float px, float py, int ih, int jh,
                                        const float* __restrict__ p) {
    int idx = -1;
#pragma clang loop unroll(disable)
    for (int s = 0; s < 4; ++s) {
        int ii = ih - 1 + (s >> 1), jj = jh - 1 + (s & 1);   // ascending cell
        if ((unsigned)ii > 4u || (unsigned)jj > 4u) continue;
        int c = 5 * ii + jj;
        const float* cell = p + 28 * c;
        float ax = cell[1], ay = cell[2], bx = cell[3], by = cell[4], cx = cell[5], cy = cell[6];
        float e0 = (px - ax) * (by - ay) - (py - ay) * (bx - ax);
        float e1 = (px - bx) * (cy - by) - (py - by) * (cx - bx);
        float e2 = (px - cx) * (ay - cy) - (py - cy) * (ax - cx);
        bool tin = (e0 >= 0.f && e1 >= 0.f && e2 >= 0.f) ||
                   (e0 <= 0.f && e1 <= 0.f && e2 <= 0.f);
        if (tin) idx = 3 * c;
        float dx = px - cell[12], dy = py - cell[13];
        if (dx * dx + dy * dy <= cell[14] * cell[14]) idx = 3 * c + 1;
        float u = (px - cell[20]) / cell[22];   // IEEE division, numpy order
        float v = (py - cell[21]) / cell[23];
        if (u * u + v * v <= 1.0f) idx = 3 * c + 2;
    }
    return idx;
}

__global__ __launch_bounds__(256) void vg_fused(const float* __restrict__ x,
                                                const float* __restrict__ p,
                                                float* __restrict__ out) {
    __shared__ float lds[LDS_FLOATS];
    int tl = threadIdx.x;
    int t  = blockIdx.x * 256 + tl;

    // ---- build padded packed cell table (threads 0..48) ----
    if (tl < 49) {
        int gi = tl / 7, gj = tl % 7;
        float* o = lds + tl * 20;
        if (gi >= 1 && gi <= 5 && gj >= 1 && gj <= 5) {
            int c = (gi - 1) * 5 + (gj - 1);
            const float* cell = p + c * 28;
            float ax = cell[1], ay = cell[2], bx = cell[3], by = cell[4], cx = cell[5], cy = cell[6];
            float d0y = by - ay, d0x = bx - ax;   // numpy-rounded diffs
            float d1y = cy - by, d1x = cx - bx;
            float d2y = ay - cy, d2x = ax - cx;
            o[0] = d0y; o[1] = -d0x; o[2] = (float)((double)ay * (double)d0x - (double)ax * (double)d0y);
            o[3] = d1y; o[4] = -d1x; o[5] = (float)((double)by * (double)d1x - (double)bx * (double)d1y);
            o[6] = d2y; o[7] = -d2x; o[8] = (float)((double)cy * (double)d2x - (double)cx * (double)d2y);
            o[9]  = cell[12]; o[10] = cell[13]; o[11] = cell[14] * cell[14];
            o[12] = cell[20]; o[13] = cell[21]; o[14] = 1.0f / cell[22]; o[15] = 1.0f / cell[23];
        } else {
            // dummy border cell: all three tests false, never within any band
            o[0] = 0.f; o[1] = 0.f; o[2] = 10.f;    // e0 = +10
            o[3] = 0.f; o[4] = 0.f; o[5] = -10.f;   // e1 = -10 -> mixed signs
            o[6] = 0.f; o[7] = 0.f; o[8] = 0.f;
            o[9] = 0.f; o[10] = 0.f; o[11] = -10.f; // tc >= 0 > r2, gap >= 10
            o[12] = 1000.f; o[13] = 1000.f; o[14] = 1.f; o[15] = 1.f;  // te ~ 1e6
        }
        o[16] = 0.f; o[17] = 0.f; o[18] = 0.f; o[19] = 0.f;
    }
    // ---- build color table (threads 128..203 -> entries 0..75) ----
    if (tl >= 128 && tl < 204) {
        int e = tl - 128;
        float* col = lds + L_COL + e * 4;
        if (e < 75) {
            int c = e / 3, kind = e - 3 * c;
            const float* cell = p + c * 28;
            int base = (kind == 0) ? 8 : (kind == 1) ? 16 : 25;
            col[0] = cell[base]; col[1] = cell[base + 1]; col[2] = cell[base + 2];
        } else {
            col[0] = 0.f; col[1] = 0.f; col[2] = 0.f;   // no-hit -> black
        }
        col[3] = 0.f;
    }
    __syncthreads();

    // ---- load 2 points (one contiguous float4 per lane, coalesced) ----
    float4 xv = ((const float4*)x)[t];
    float PX[PPT] = {xv.x, xv.z};
    float PY[PPT] = {xv.y, xv.w};
    int idx[PPT], ih[PPT], jh[PPT];
    bool unc[PPT];

#pragma unroll
    for (int k = 0; k < PPT; ++k) {
        // padded candidate block rows/cols {ih, ih+1}; ih = floor(5X+0.4025)
        // in [0,5] (reach 0.0805 >= 0.08 shape reach + fp slack; r4-r7 proven)
        ih[k] = (int)floorf(__builtin_fmaf(PX[k], 5.0f, 0.4025f));
        jh[k] = (int)floorf(__builtin_fmaf(PY[k], 5.0f, 0.4025f));
        idx[k] = -1; unc[k] = false;
    }

#pragma unroll
    for (int k = 0; k < PPT; ++k) {
        float X = PX[k], Y = PY[k];
        // Phase 1: 16 unconditional ds_read_b128, all at immediate offsets
        // {0,80,560,640}+{0,16,32,48} B from one base address -> MLP=16.
        const float* base = lds + (7 * ih[k] + jh[k]) * 20;
        float4 Q[4][4];
#pragma unroll
        for (int s = 0; s < 4; ++s) {
            const float4* c4 = (const float4*)(base + ((s >> 1) * 140 + (s & 1) * 20));
            Q[s][0] = c4[0]; Q[s][1] = c4[1]; Q[s][2] = c4[2]; Q[s][3] = c4[3];
        }

        // Phase 2: pure select-gated evaluation, no masks needed (dummy cells
        // inert; real-but-unneeded cells can't hit: hit => within window).
#pragma unroll
        for (int s = 0; s < 4; ++s) {
            float4 q0 = Q[s][0], q1 = Q[s][1], q2 = Q[s][2], q3 = Q[s][3];
            int gi = ih[k] + (s >> 1), gj = jh[k] + (s & 1);
            int sid = 15 * gi + 3 * gj - 18;   // 3*(5*(gi-1)+(gj-1)); ascending in s

            // triangle: affine screen, 2-sided band
            float e0 = __builtin_fmaf(X, q0.x, __builtin_fmaf(Y, q0.y, q0.z));
            float e1 = __builtin_fmaf(X, q0.w, __builtin_fmaf(Y, q1.x, q1.y));
            float e2 = __builtin_fmaf(X, q1.z, __builtin_fmaf(Y, q1.w, q2.x));
            float lo = __builtin_fminf(__builtin_fminf(e0, e1), e2);
            float hi = __builtin_fmaxf(__builtin_fmaxf(e0, e1), e2);
            bool ts = (lo >= EPS_T) || (hi <= -EPS_T);
            bool tr = (lo >= -EPS_T) || (hi <= EPS_T);
            unc[k] = unc[k] | (ts != tr);
            idx[k] = ts ? sid : idx[k];

            // circle: centered fma screen
            float dx = X - q2.y, dy = Y - q2.z;
            float tc = __builtin_fmaf(dx, dx, dy * dy);
            unc[k] = unc[k] | (__builtin_fabsf(tc - q2.w) < EPS_C);
            idx[k] = (tc <= q2.w) ? sid + 1 : idx[k];

            // ellipse: reciprocal screen
            float ex = X - q3.x, ey = Y - q3.y;
            float u = ex * q3.z, v = ey * q3.w;
            float te = __builtin_fmaf(u, u, v * v);
            unc[k] = unc[k] | (__builtin_fabsf(te - 1.0f) < EPS_E);
            idx[k] = (te <= 1.0f) ? sid + 2 : idx[k];
        }
    }

    // rare bit-exact fallback for band-flagged points
#pragma unroll
    for (int k = 0; k < PPT; ++k)
        if (__builtin_expect(unc[k], 0))
            idx[k] = exact_point(PX[k], PY[k], ih[k], jh[k], p);

    // color gather from LDS (entry 75 = black) + coalesced 8B stores
    const float4* col4 = (const float4*)(lds + L_COL);
    float4 c0 = col4[idx[0] < 0 ? 75 : idx[0]];
    float4 c1 = col4[idx[1] < 0 ? 75 : idx[1]];

    float2* o2 = (float2*)out;
    o2[3 * t + 0] = make_float2(c0.x, c0.y);
    o2[3 * t + 1] = make_float2(c0.z, c1.x);
    o2[3 * t + 2] = make_float2(c1.y, c1.z);
}

extern "C" void kernel_launch(void* const* d_in, const int* in_sizes, int n_in,
                              void* d_out, int out_size, void* d_ws, size_t ws_size,
                              hipStream_t stream) {
    const float* x = (const float*)d_in[0];   // (NPTS, 2) fp32
    const float* p = (const float*)d_in[1];   // (700,)   fp32
    float* out = (float*)d_out;               // (NPTS, 3) fp32
    (void)d_ws; (void)ws_size;

    vg_fused<<<NTHREADS / 256, 256, 0, stream>>>(x, p, out);
}